// Round 5
// baseline (39.515 us; speedup 1.0000x reference)
//
#include <hip/hip_runtime.h>

// Problem geometry (fixed by the reference): B=4096, T=1024, D=6.
#define NROWS   (4096 * 1024)         // B*T rows of 6 floats
#define NFLOAT4 (NROWS * 6 / 4)       // 6,291,456 float4 per input
#define NELEM_PER_CAT (NROWS * 3)     // denominator for each mean (B*T*3)

#define BLOCKS  8192
#define THREADS 256
#define STEP    (BLOCKS * THREADS)    // 2,097,152 threads; NFLOAT4/STEP == 3 exactly
// STEP % 3 == 2: thread's float4-index pattern (j % 3) rotates 0 -> 2 -> 1.

__device__ __forceinline__ float norm_angle(float a) {
    const float PI     = 3.14159265358979323846f;
    const float TWO_PI = 6.28318530717958647692f;
    a = (a >  PI) ? a - TWO_PI : a;
    a = (a < -PI) ? a + TWO_PI : a;
    return a;
}

// rot bitmask per pattern (bit c set => component c is a rotation channel)
// pattern 0: ch0,1,2,3 -> 0b1000 ; pattern 1: ch4,5,0,1 -> 0b0011 ; pattern 2: ch2,3,4,5 -> 0b1110
__device__ __forceinline__ int rot_mask(int pat) {
    return pat == 0 ? 0x8 : (pat == 1 ? 0x3 : 0xE);
}

__device__ __forceinline__ void proc_c(float a, float b, bool rot, float& ts, float& rs) {
    float dp = a - b;
    float dn = norm_angle(a) - norm_angle(b);
    ts += rot ? 0.0f : dp * dp;
    rs += rot ? dn * dn : 0.0f;
}

__device__ __forceinline__ void proc4(float4 p, float4 t, int mask, float& ts, float& rs) {
    proc_c(p.x, t.x, (mask & 1) != 0, ts, rs);
    proc_c(p.y, t.y, (mask & 2) != 0, ts, rs);
    proc_c(p.z, t.z, (mask & 4) != 0, ts, rs);
    proc_c(p.w, t.w, (mask & 8) != 0, ts, rs);
}

__global__ void __launch_bounds__(THREADS) wmse_main_kernel(
        const float4* __restrict__ pred, const float4* __restrict__ targ,
        float2* __restrict__ partials) {
    const int j = blockIdx.x * THREADS + threadIdx.x;   // coalesced within wave

    // All 6 independent loads issued up front.
    float4 p0 = pred[j];
    float4 p1 = pred[j + STEP];
    float4 p2 = pred[j + 2 * STEP];
    float4 t0 = targ[j];
    float4 t1 = targ[j + STEP];
    float4 t2 = targ[j + 2 * STEP];

    // Force all 24 result registers live here: compiler must issue all 6
    // global_load_dwordx4 back-to-back before a single vmcnt wait, instead
    // of the 2-deep load->use serialization it chose at VGPR_Count=20.
    asm volatile("" : "+v"(p0.x), "+v"(p0.y), "+v"(p0.z), "+v"(p0.w),
                      "+v"(p1.x), "+v"(p1.y), "+v"(p1.z), "+v"(p1.w),
                      "+v"(p2.x), "+v"(p2.y), "+v"(p2.z), "+v"(p2.w),
                      "+v"(t0.x), "+v"(t0.y), "+v"(t0.z), "+v"(t0.w),
                      "+v"(t1.x), "+v"(t1.y), "+v"(t1.z), "+v"(t1.w),
                      "+v"(t2.x), "+v"(t2.y), "+v"(t2.z), "+v"(t2.w));

    const int pat = j % 3;
    const int m0 = rot_mask(pat);
    const int m1 = rot_mask((pat + 2) % 3);
    const int m2 = rot_mask((pat + 1) % 3);

    float ts = 0.0f, rs = 0.0f;
    proc4(p0, t0, m0, ts, rs);
    proc4(p1, t1, m1, ts, rs);
    proc4(p2, t2, m2, ts, rs);

    // wave64 butterfly reduce
    #pragma unroll
    for (int off = 32; off > 0; off >>= 1) {
        ts += __shfl_down(ts, off, 64);
        rs += __shfl_down(rs, off, 64);
    }
    __shared__ float sts[4], srs[4];
    const int wave = threadIdx.x >> 6, lane = threadIdx.x & 63;
    if (lane == 0) { sts[wave] = ts; srs[wave] = rs; }
    __syncthreads();
    if (threadIdx.x == 0) {
        float t = sts[0] + sts[1] + sts[2] + sts[3];
        float r = srs[0] + srs[1] + srs[2] + srs[3];
        partials[blockIdx.x] = make_float2(t, r);  // private slot: no contention
    }
}

__global__ void __launch_bounds__(1024) wmse_final_kernel(
        const float2* __restrict__ partials, float* __restrict__ out) {
    // 8192 partials, 1024 threads: each reads 8 (as 4x float4)
    const float4* p4 = (const float4*)partials;   // 4096 float4
    float ts = 0.0f, rs = 0.0f;
    #pragma unroll
    for (int k = 0; k < 4; ++k) {
        float4 v = p4[threadIdx.x + k * 1024];
        ts += v.x + v.z;
        rs += v.y + v.w;
    }

    #pragma unroll
    for (int off = 32; off > 0; off >>= 1) {
        ts += __shfl_down(ts, off, 64);
        rs += __shfl_down(rs, off, 64);
    }
    __shared__ float sts[16], srs[16];
    const int wave = threadIdx.x >> 6, lane = threadIdx.x & 63;
    if (lane == 0) { sts[wave] = ts; srs[wave] = rs; }
    __syncthreads();
    if (threadIdx.x == 0) {
        double t = 0.0, r = 0.0;
        #pragma unroll
        for (int w = 0; w < 16; ++w) { t += (double)sts[w]; r += (double)srs[w]; }
        double inv_n = 1.0 / (double)NELEM_PER_CAT;
        double trans = t * inv_n * 1.0;    // TRANS_WEIGHT
        double rot   = r * inv_n * 100.0;  // ROT_WEIGHT
        out[0] = (float)(trans + rot);  // total
        out[1] = (float)trans;
        out[2] = (float)rot;
    }
}

extern "C" void kernel_launch(void* const* d_in, const int* in_sizes, int n_in,
                              void* d_out, int out_size, void* d_ws, size_t ws_size,
                              hipStream_t stream) {
    const float4* pred = (const float4*)d_in[0];
    const float4* targ = (const float4*)d_in[1];
    float2* partials = (float2*)d_ws;   // 8192 * 8 B = 64 KB
    float* out = (float*)d_out;

    wmse_main_kernel<<<BLOCKS, THREADS, 0, stream>>>(pred, targ, partials);
    wmse_final_kernel<<<1, 1024, 0, stream>>>(partials, out);
}

// Round 6
// 37.156 us; speedup vs baseline: 1.0635x; 1.0635x over previous
//
#include <hip/hip_runtime.h>

// Problem geometry (fixed by the reference): B=4096, T=1024, D=6.
#define NROWS   (4096 * 1024)         // B*T rows of 6 floats
#define NFLOAT4 (NROWS * 6 / 4)       // 6,291,456 float4 per input
#define NELEM_PER_CAT (NROWS * 3)     // denominator for each mean (B*T*3)

#define BLOCKS  8192
#define THREADS 256
#define STEP    (BLOCKS * THREADS)    // 2,097,152 threads; NFLOAT4/STEP == 3 exactly
// STEP % 3 == 2: thread's float4-index pattern (j % 3) rotates 0 -> 2 -> 1.

__device__ __forceinline__ float norm_angle(float a) {
    const float PI     = 3.14159265358979323846f;
    const float TWO_PI = 6.28318530717958647692f;
    a = (a >  PI) ? a - TWO_PI : a;
    a = (a < -PI) ? a + TWO_PI : a;
    return a;
}

// rot bitmask per pattern (bit c set => component c is a rotation channel)
// pattern 0: ch0,1,2,3 -> 0b1000 ; pattern 1: ch4,5,0,1 -> 0b0011 ; pattern 2: ch2,3,4,5 -> 0b1110
__device__ __forceinline__ int rot_mask(int pat) {
    return pat == 0 ? 0x8 : (pat == 1 ? 0x3 : 0xE);
}

__device__ __forceinline__ void proc_c(float a, float b, bool rot, float& ts, float& rs) {
    float dp = a - b;
    float dn = norm_angle(a) - norm_angle(b);
    ts += rot ? 0.0f : dp * dp;
    rs += rot ? dn * dn : 0.0f;
}

__device__ __forceinline__ void proc4(float4 p, float4 t, int mask, float& ts, float& rs) {
    proc_c(p.x, t.x, (mask & 1) != 0, ts, rs);
    proc_c(p.y, t.y, (mask & 2) != 0, ts, rs);
    proc_c(p.z, t.z, (mask & 4) != 0, ts, rs);
    proc_c(p.w, t.w, (mask & 8) != 0, ts, rs);
}

__global__ void __launch_bounds__(THREADS) wmse_main_kernel(
        const float4* __restrict__ pred, const float4* __restrict__ targ,
        float2* __restrict__ partials) {
    const int j = blockIdx.x * THREADS + threadIdx.x;   // coalesced within wave

    // All 6 independent loads issued up front.
    float4 p0 = pred[j];
    float4 p1 = pred[j + STEP];
    float4 p2 = pred[j + 2 * STEP];
    float4 t0 = targ[j];
    float4 t1 = targ[j + STEP];
    float4 t2 = targ[j + 2 * STEP];

    const int pat = j % 3;
    const int m0 = rot_mask(pat);
    const int m1 = rot_mask((pat + 2) % 3);
    const int m2 = rot_mask((pat + 1) % 3);

    float ts = 0.0f, rs = 0.0f;
    proc4(p0, t0, m0, ts, rs);
    proc4(p1, t1, m1, ts, rs);
    proc4(p2, t2, m2, ts, rs);

    // wave64 butterfly reduce
    #pragma unroll
    for (int off = 32; off > 0; off >>= 1) {
        ts += __shfl_down(ts, off, 64);
        rs += __shfl_down(rs, off, 64);
    }
    __shared__ float sts[4], srs[4];
    const int wave = threadIdx.x >> 6, lane = threadIdx.x & 63;
    if (lane == 0) { sts[wave] = ts; srs[wave] = rs; }
    __syncthreads();
    if (threadIdx.x == 0) {
        float t = sts[0] + sts[1] + sts[2] + sts[3];
        float r = srs[0] + srs[1] + srs[2] + srs[3];
        partials[blockIdx.x] = make_float2(t, r);  // private slot: no contention
    }
}

__global__ void __launch_bounds__(1024) wmse_final_kernel(
        const float2* __restrict__ partials, float* __restrict__ out) {
    // 8192 partials, 1024 threads: each reads 8 (as 4x float4)
    const float4* p4 = (const float4*)partials;   // 4096 float4
    float ts = 0.0f, rs = 0.0f;
    #pragma unroll
    for (int k = 0; k < 4; ++k) {
        float4 v = p4[threadIdx.x + k * 1024];
        ts += v.x + v.z;
        rs += v.y + v.w;
    }

    #pragma unroll
    for (int off = 32; off > 0; off >>= 1) {
        ts += __shfl_down(ts, off, 64);
        rs += __shfl_down(rs, off, 64);
    }
    __shared__ float sts[16], srs[16];
    const int wave = threadIdx.x >> 6, lane = threadIdx.x & 63;
    if (lane == 0) { sts[wave] = ts; srs[wave] = rs; }
    __syncthreads();
    if (threadIdx.x == 0) {
        double t = 0.0, r = 0.0;
        #pragma unroll
        for (int w = 0; w < 16; ++w) { t += (double)sts[w]; r += (double)srs[w]; }
        double inv_n = 1.0 / (double)NELEM_PER_CAT;
        double trans = t * inv_n * 1.0;    // TRANS_WEIGHT
        double rot   = r * inv_n * 100.0;  // ROT_WEIGHT
        out[0] = (float)(trans + rot);  // total
        out[1] = (float)trans;
        out[2] = (float)rot;
    }
}

extern "C" void kernel_launch(void* const* d_in, const int* in_sizes, int n_in,
                              void* d_out, int out_size, void* d_ws, size_t ws_size,
                              hipStream_t stream) {
    const float4* pred = (const float4*)d_in[0];
    const float4* targ = (const float4*)d_in[1];
    float2* partials = (float2*)d_ws;   // 8192 * 8 B = 64 KB
    float* out = (float*)d_out;

    wmse_main_kernel<<<BLOCKS, THREADS, 0, stream>>>(pred, targ, partials);
    wmse_final_kernel<<<1, 1024, 0, stream>>>(partials, out);
}